// Round 1
// 79.960 us; speedup vs baseline: 1.0097x; 1.0097x over previous
//
#include <hip/hip_runtime.h>
#include <math.h>

#define BLK 256
#define NX 8              // x-points per thread
#define NPTS 4096
#define SLICES 16         // y-slices per block (one per lane-group t&15)
#define SLICE 256         // y per slice
#define XT 32             // x-tiles per (dir, b)
#define XPB 128           // x per block = 16 octets * 8

// Fused kernel: block = (dir, b, x-tile of 128). All 4096 y staged in 64 KiB
// LDS (exactly the static limit -> 2 blocks/CU, 8 waves/CU). Thread t owns
// x-octet (t>>4) and y-slice (t&15): 8 x * 256 y, NX=8 keeps total LDS read
// traffic at 536 MB (~7.8 us on DS pipe, under the 12 us VALU floor).
//
// Bank handling: slice stride 256 float4 puts all 16 slices in the same
// bank-quad (16-way conflict). Staging XOR-swizzles slot jj -> jj^(s&7); the
// compute loop reads sp[w + (d^ (s&7))] so each ds_read_b128 spreads over all
// 8 bank-quads, 2 addresses each = 2-way = free (m136), zero memory overhead
// (a +1 pad would blow the 64 KiB static limit).
//
// Per-x min across the 16 slices: 4 rounds of __shfl_xor (masks 1,2,4,8 stay
// inside the 16-lane slice group). One plain float store per block; no
// partials (removes the 4 MB HBM/L3 round-trip of the old k1+k2), no
// atomics, no out-zeroing.
//
// Session context: the ~41 us fillBufferAligned rows in rocprof are the
// harness's 256 MiB workspace re-poison inside the timed window - fixed
// overhead we cannot touch. Prior notes: R3 atomicMin write-through = never;
// R6 grid.sync = +50 us; k1 floor ~15 us. This removes k2's work instead.
__global__ __launch_bounds__(BLK, 2) void chamfer_fused_kernel(
    const float* __restrict__ X, const float* __restrict__ Y,
    float* __restrict__ sums)
{
  __shared__ float4 sh[NPTS];   // 65536 B exactly

  int lin = blockIdx.x;
  int xt  = lin & 31; lin >>= 5;
  int b   = lin & 7;
  int dir = lin >> 3;

  const float* xs = (dir ? Y : X) + b * (NPTS * 3);
  const float* ys = (dir ? X : Y) + b * (NPTS * 3);

  int t = threadIdx.x;

  // Stage all y: thread t stages y = r*256 + t at float4-slot
  // r*256 + (t ^ (r&7)). Writes: consecutive-range distinct addresses per
  // instruction (XOR by a wave-uniform constant) -> no write conflicts.
  // Global reads: 12 B/lane stride, coalesced; inputs are L2/L3-hot.
  #pragma unroll
  for (int r = 0; r < SLICES; ++r) {
    const float* yp = ys + (r * SLICE + t) * 3;
    float y0 = yp[0], y1 = yp[1], y2 = yp[2];
    sh[r * SLICE + (t ^ (r & 7))] =
        make_float4(y0, y1, y2, 0.5f * (y0 * y0 + y1 * y1 + y2 * y2));
  }

  // This thread's 8 x-points (24 contiguous floats, 16B-aligned). The 16
  // threads of an s-group load the same 96 B redundantly - L2-hit, cheap.
  int x0i = xt * XPB + (t >> 4) * NX;
  float xf[NX * 3];
  {
    const float4* xp = reinterpret_cast<const float4*>(xs + x0i * 3);
    #pragma unroll
    for (int i = 0; i < 6; ++i) {
      float4 p = xp[i];
      xf[i * 4 + 0] = p.x; xf[i * 4 + 1] = p.y;
      xf[i * 4 + 2] = p.z; xf[i * 4 + 3] = p.w;
    }
  }
  float n0[NX], n1[NX], n2[NX], x2h[NX], gm[NX];
  #pragma unroll
  for (int k = 0; k < NX; ++k) {
    float a = xf[k * 3 + 0], bb = xf[k * 3 + 1], cc = xf[k * 3 + 2];
    n0[k] = -a; n1[k] = -bb; n2[k] = -cc;
    x2h[k] = 0.5f * (a * a + bb * bb + cc * cc);
    gm[k] = __builtin_inff();
  }

  __syncthreads();

  int s  = t & 15;        // y-slice
  int mk = s & 7;         // bank swizzle key
  const float4* sp = sh + s * SLICE;
  int o0 = 0 ^ mk, o1 = 1 ^ mk, o2 = 2 ^ mk, o3 = 3 ^ mk;
  int o4 = 4 ^ mk, o5 = 5 ^ mk, o6 = 6 ^ mk, o7 = 7 ^ mk;

  // Per 8 y x 8 x: 24 FMA + 4 v_min3 per k (3.5 VALU/pair). Reading slot
  // w + (d^mk) yields y = w + d (w multiple of 8): full coverage, any order.
  #pragma unroll 2
  for (int w = 0; w < SLICE; w += 8) {
    float4 p0 = sp[w + o0], p1 = sp[w + o1], p2 = sp[w + o2], p3 = sp[w + o3];
    float4 p4 = sp[w + o4], p5 = sp[w + o5], p6 = sp[w + o6], p7 = sp[w + o7];
    #pragma unroll
    for (int k = 0; k < NX; ++k) {
      float g0 = fmaf(n0[k], p0.x, fmaf(n1[k], p0.y, fmaf(n2[k], p0.z, p0.w)));
      float g1 = fmaf(n0[k], p1.x, fmaf(n1[k], p1.y, fmaf(n2[k], p1.z, p1.w)));
      float g2 = fmaf(n0[k], p2.x, fmaf(n1[k], p2.y, fmaf(n2[k], p2.z, p2.w)));
      float g3 = fmaf(n0[k], p3.x, fmaf(n1[k], p3.y, fmaf(n2[k], p3.z, p3.w)));
      float g4 = fmaf(n0[k], p4.x, fmaf(n1[k], p4.y, fmaf(n2[k], p4.z, p4.w)));
      float g5 = fmaf(n0[k], p5.x, fmaf(n1[k], p5.y, fmaf(n2[k], p5.z, p5.w)));
      float g6 = fmaf(n0[k], p6.x, fmaf(n1[k], p6.y, fmaf(n2[k], p6.z, p6.w)));
      float g7 = fmaf(n0[k], p7.x, fmaf(n1[k], p7.y, fmaf(n2[k], p7.z, p7.w)));
      float m0 = fminf(fminf(g0, g1), g2);            // v_min3
      float m1 = fminf(fminf(g3, g4), g5);            // v_min3
      float m2 = fminf(fminf(m0, m1), g6);            // v_min3
      gm[k]    = fminf(fminf(m2, g7), gm[k]);         // v_min3
    }
  }

  // Min across the 16 slice lanes (t&15 group is lane-contiguous; xor masks
  // < 16 stay inside the group).
  #pragma unroll
  for (int mm = 1; mm < 16; mm <<= 1) {
    #pragma unroll
    for (int k = 0; k < NX; ++k)
      gm[k] = fminf(gm[k], __shfl_xor(gm[k], mm, 64));
  }

  // Octet sum on slice-lane 0 only; butterfly-sum the 4 octets of the wave.
  float v = 0.0f;
  #pragma unroll
  for (int k = 0; k < NX; ++k) v += 2.0f * (x2h[k] + gm[k]);
  if (s != 0) v = 0.0f;
  #pragma unroll
  for (int mm = 1; mm < 64; mm <<= 1) v += __shfl_xor(v, mm, 64);

  __syncthreads();                      // all waves done reading sh
  float* red = reinterpret_cast<float*>(sh);
  if ((t & 63) == 0) red[t >> 6] = v;
  __syncthreads();
  if (t == 0) sums[blockIdx.x] = red[0] + red[1] + red[2] + red[3];
}

// Final combine: 512 block sums (2 KB, written last kernel -> L2-hot) into
// out[8]. Single writer per batch: no atomics, no pre-zero dispatch.
// sums[bid], bid = (dir*8+b)*32 + xt.
__global__ __launch_bounds__(512) void chamfer_final_kernel(
    const float* __restrict__ sums, float* __restrict__ out)
{
  __shared__ float gred[16];
  int t = threadIdx.x;
  float v = sums[t];
  #pragma unroll
  for (int mm = 1; mm < 32; mm <<= 1) v += __shfl_xor(v, mm, 64);
  if ((t & 31) == 0) gred[t >> 5] = v;   // group = dir*8 + b
  __syncthreads();
  if (t < 8) out[t] = (gred[t] + gred[t + 8]) * (1.0f / 4096.0f);
}

// Fallback (workspace too small): full y range per block, direct reduction.
__global__ __launch_bounds__(BLK, 2) void chamfer_direct_kernel(
    const float* __restrict__ X, const float* __restrict__ Y,
    float* __restrict__ out)
{
  extern __shared__ float4 shd[];
  int lin = blockIdx.x;
  int xt  = lin & 1;  lin >>= 1;
  int b   = lin & 7;
  int dir = lin >> 3;
  const float* xs = (dir ? Y : X) + b * (NPTS * 3);
  const float* ys = (dir ? X : Y) + b * (NPTS * 3);

  for (int j = threadIdx.x; j < NPTS; j += BLK) {
    float y0 = ys[j * 3 + 0], y1 = ys[j * 3 + 1], y2 = ys[j * 3 + 2];
    shd[j] = make_float4(y0, y1, y2, 0.5f * (y0 * y0 + y1 * y1 + y2 * y2));
  }
  __syncthreads();

  int x0i = xt * (BLK * 8) + threadIdx.x * 8;
  float xf[24];
  const float4* xp = reinterpret_cast<const float4*>(xs + x0i * 3);
  #pragma unroll
  for (int i = 0; i < 6; ++i) {
    float4 p = xp[i];
    xf[i * 4 + 0] = p.x; xf[i * 4 + 1] = p.y;
    xf[i * 4 + 2] = p.z; xf[i * 4 + 3] = p.w;
  }
  float n0[8], n1[8], n2[8], x2h[8], gm[8];
  #pragma unroll
  for (int k = 0; k < 8; ++k) {
    float a = xf[k * 3 + 0], bb = xf[k * 3 + 1], cc = xf[k * 3 + 2];
    n0[k] = -a; n1[k] = -bb; n2[k] = -cc;
    x2h[k] = 0.5f * (a * a + bb * bb + cc * cc);
    gm[k] = __builtin_inff();
  }
  for (int j = 0; j < NPTS; j += 4) {
    float4 p0 = shd[j], p1 = shd[j + 1], p2 = shd[j + 2], p3 = shd[j + 3];
    #pragma unroll
    for (int k = 0; k < 8; ++k) {
      float ga = fmaf(n0[k], p0.x, fmaf(n1[k], p0.y, fmaf(n2[k], p0.z, p0.w)));
      float gb = fmaf(n0[k], p1.x, fmaf(n1[k], p1.y, fmaf(n2[k], p1.z, p1.w)));
      float gc = fmaf(n0[k], p2.x, fmaf(n1[k], p2.y, fmaf(n2[k], p2.z, p2.w)));
      float gd = fmaf(n0[k], p3.x, fmaf(n1[k], p3.y, fmaf(n2[k], p3.z, p3.w)));
      float m  = fminf(fminf(ga, gb), gc);
      gm[k] = fminf(fminf(m, gd), gm[k]);
    }
  }
  float v = 0.0f;
  #pragma unroll
  for (int k = 0; k < 8; ++k) v += 2.0f * (x2h[k] + gm[k]);
  #pragma unroll
  for (int off = 32; off > 0; off >>= 1) v += __shfl_down(v, off, 64);
  __syncthreads();
  float* red = reinterpret_cast<float*>(shd);
  if ((threadIdx.x & 63) == 0) red[threadIdx.x >> 6] = v;
  __syncthreads();
  if (threadIdx.x == 0) {
    float s2 = red[0] + red[1] + red[2] + red[3];
    atomicAdd(&out[b], s2 * (1.0f / 4096.0f));
  }
}

__global__ void zero_out_kernel(float* out)
{
  if (threadIdx.x < 8) out[threadIdx.x] = 0.0f;
}

extern "C" void kernel_launch(void* const* d_in, const int* in_sizes, int n_in,
                              void* d_out, int out_size, void* d_ws, size_t ws_size,
                              hipStream_t stream)
{
  const float* X = (const float*)d_in[0];
  const float* Y = (const float*)d_in[1];
  float* out = (float*)d_out;

  if (ws_size >= (size_t)(2 * 8 * XT) * sizeof(float)) {
    // 512 blocks = 2 dirs * 8 batches * 32 x-tiles; 2 blocks/CU (64 KiB LDS).
    chamfer_fused_kernel<<<2 * 8 * XT, BLK, 0, stream>>>(X, Y, (float*)d_ws);
    chamfer_final_kernel<<<1, 512, 0, stream>>>((const float*)d_ws, out);
  } else {
    zero_out_kernel<<<1, 64, 0, stream>>>(out);
    chamfer_direct_kernel<<<2 * 8 * 2, BLK, NPTS * sizeof(float4), stream>>>(
        X, Y, out);
  }
}

// Round 2
// 70.878 us; speedup vs baseline: 1.1391x; 1.1281x over previous
//
#include <hip/hip_runtime.h>
#include <math.h>

#define BLK 256
#define NPTS 4096
#define XT 32             // x-tiles of 128 per (dir, b)

using short8 = __attribute__((ext_vector_type(8))) short;
using f32x4  = __attribute__((ext_vector_type(4))) float;

// bf16 RNE helpers (no NaN concern for this data).
__device__ inline unsigned short f2bf(float f) {
  unsigned u = __float_as_uint(f);
  return (unsigned short)((u + 0x7FFFu + ((u >> 16) & 1u)) >> 16);
}
__device__ inline float bf2f(unsigned short h) {
  return __uint_as_float((unsigned)h << 16);
}
__device__ inline unsigned pk(unsigned short lo, unsigned short hi) {
  return (unsigned)lo | ((unsigned)hi << 16);
}

// MFMA chamfer kernel. Math: dist = (-2*x.y + y^2)_MFMA + x^2_fp32.
// fp32 emulated via bf16 2-term splits; K=32 slot map (A = y-record, B = x):
//   k0-2 : yh_i         * -2xh_i        k3-5 : yl_i * -2xh_i
//   k6-8 : yh_i         * -2xl_i        k9-11: yl_i * -2xl_i   (all 4 cross
//   k12-14: y2h,y2m,y2l * 1.0            products kept; resid ~2^-18|x||y|)
//   k15-31: 0 (A lanes 32-63 read duplicate addrs = broadcast; B groups 2,3
//   are zeroed so their garbage contributes 0)
// x^2 is lane-constant (col = lane&15) so it's added AFTER the min, in fp32,
// exactly. y^2 3-term split error ~2^-27*y2. Expected out error ~1e-5.
//
// Swapped orientation: A = 16 y (M rows), B = 16 x (N cols) => lane's 4 acc
// regs are 4 y-rows of its x-col (C/D: col=lane&15, row=(lane>>4)*4+reg,
// m89/m91-verified) => min over y is 2 fminf trees/MFMA + 2 shfl_xor at end.
//
// Per wave: 32 x (2 B-frags), loop 256 y-tiles: 1 ds_read_b128 + 2 MFMA +
// 4 min. Pipe totals (per-SIMD, 2 waves): MFMA 2.1us, VALU ~3.4us (incl
// staging), DS 3.4us (268MB A-frag reads) -> ~5us overlapped, vs the 12us
// fp32 VALU floor (3 FMA/pair; CDNA4 has no packed-fp32 doubling).
//
// LDS: y-records SoA: word0 (k0-7) in rec[0..2048), word1 (k8-15) in
// rec[2048..4096), 16B each = 64 KiB. SoA => staging writes stride-16B
// (conflict-free) and frag reads are 4-way/quad = bandwidth minimum.
// 4096 y staged in 2 passes of 2048.
//
// Harness context: ~40us of the 80us window is the 256MiB ws re-poison
// (fillBufferAligned rows) - not controllable from kernel code.
__global__ __launch_bounds__(BLK, 2) void chamfer_mfma_kernel(
    const float* __restrict__ X, const float* __restrict__ Y,
    float* __restrict__ sums)
{
  __shared__ uint4 rec[4096];   // [2][2048] SoA record words, 64 KiB

  int bid = blockIdx.x;
  int xt  = bid & 31;
  int b   = (bid >> 5) & 7;
  int dir = bid >> 8;

  const float* xs = (dir ? Y : X) + b * (NPTS * 3);
  const float* ys = (dir ? X : Y) + b * (NPTS * 3);

  int t = threadIdx.x;
  int lane = t & 63;
  int w = t >> 6;
  int g = lane >> 4;     // k-slice group 0..3
  int c = lane & 15;     // x col within tile

  // ---- B-frags (x side), fixed for the whole kernel ----
  int xbase = xt * 128 + w * 32;
  const float* xpa = xs + (xbase + c) * 3;
  const float* xpb = xs + (xbase + 16 + c) * 3;
  float xa0 = xpa[0], xa1 = xpa[1], xa2 = xpa[2];
  float xb0 = xpb[0], xb1 = xpb[1], xb2 = xpb[2];
  float x2a = fmaf(xa0, xa0, fmaf(xa1, xa1, xa2 * xa2));
  float x2b = fmaf(xb0, xb0, fmaf(xb1, xb1, xb2 * xb2));

  const unsigned short ONE = 0x3F80;
  short8 b0f = (short8)0, b1f = (short8)0;
  {
    // splits: xh = bf16(x), xl = bf16(x - xh); B holds -2*xh, -2*xl (exact
    // bf16 scalings).
    unsigned short ha0 = f2bf(xa0), ha1 = f2bf(xa1), ha2 = f2bf(xa2);
    unsigned short la0 = f2bf(xa0 - bf2f(ha0));
    unsigned short la1 = f2bf(xa1 - bf2f(ha1));
    unsigned short la2 = f2bf(xa2 - bf2f(ha2));
    unsigned short hb0 = f2bf(xb0), hb1 = f2bf(xb1), hb2 = f2bf(xb2);
    unsigned short lb0 = f2bf(xb0 - bf2f(hb0));
    unsigned short lb1 = f2bf(xb1 - bf2f(hb1));
    unsigned short lb2 = f2bf(xb2 - bf2f(hb2));
    unsigned short mha0 = f2bf(-2.0f * bf2f(ha0));
    unsigned short mha1 = f2bf(-2.0f * bf2f(ha1));
    unsigned short mha2 = f2bf(-2.0f * bf2f(ha2));
    unsigned short mla0 = f2bf(-2.0f * bf2f(la0));
    unsigned short mla1 = f2bf(-2.0f * bf2f(la1));
    unsigned short mla2 = f2bf(-2.0f * bf2f(la2));
    unsigned short mhb0 = f2bf(-2.0f * bf2f(hb0));
    unsigned short mhb1 = f2bf(-2.0f * bf2f(hb1));
    unsigned short mhb2 = f2bf(-2.0f * bf2f(hb2));
    unsigned short mlb0 = f2bf(-2.0f * bf2f(lb0));
    unsigned short mlb1 = f2bf(-2.0f * bf2f(lb1));
    unsigned short mlb2 = f2bf(-2.0f * bf2f(lb2));
    if (g == 0) {
      b0f[0] = mha0; b0f[1] = mha1; b0f[2] = mha2; b0f[3] = mha0;
      b0f[4] = mha1; b0f[5] = mha2; b0f[6] = mla0; b0f[7] = mla1;
      b1f[0] = mhb0; b1f[1] = mhb1; b1f[2] = mhb2; b1f[3] = mhb0;
      b1f[4] = mhb1; b1f[5] = mhb2; b1f[6] = mlb0; b1f[7] = mlb1;
    } else if (g == 1) {
      b0f[0] = mla2; b0f[1] = mla0; b0f[2] = mla1; b0f[3] = mla2;
      b0f[4] = ONE;  b0f[5] = ONE;  b0f[6] = ONE;  b0f[7] = 0;
      b1f[0] = mlb2; b1f[1] = mlb0; b1f[2] = mlb1; b1f[3] = mlb2;
      b1f[4] = ONE;  b1f[5] = ONE;  b1f[6] = ONE;  b1f[7] = 0;
    }
    // g >= 2: stay zero -> k16-31 contribute nothing.
  }

  float gm0 = __builtin_inff(), gm1 = __builtin_inff();
  f32x4 cz = {0.0f, 0.0f, 0.0f, 0.0f};
  const short8* recp = reinterpret_cast<const short8*>(rec);
  int aoff = (g & 1) * 2048 + c;   // groups 2,3 duplicate 0,1 (broadcast)

  for (int p = 0; p < 2; ++p) {
    // ---- stage 2048 y-records (SoA: word0 then word1 region) ----
    #pragma unroll
    for (int i = 0; i < 8; ++i) {
      int yl_ = t + i * 256;
      const float* yp = ys + (p * 2048 + yl_) * 3;
      float y0 = yp[0], y1 = yp[1], y2c = yp[2];
      unsigned short h0 = f2bf(y0), h1 = f2bf(y1), h2 = f2bf(y2c);
      unsigned short l0 = f2bf(y0 - bf2f(h0));
      unsigned short l1 = f2bf(y1 - bf2f(h1));
      unsigned short l2 = f2bf(y2c - bf2f(h2));
      float ysq = fmaf(y0, y0, fmaf(y1, y1, y2c * y2c));
      unsigned short s0 = f2bf(ysq);
      float r1 = ysq - bf2f(s0);
      unsigned short s1 = f2bf(r1);
      unsigned short s2 = f2bf(r1 - bf2f(s1));
      uint4 w0, w1;
      w0.x = pk(h0, h1); w0.y = pk(h2, l0); w0.z = pk(l1, l2); w0.w = pk(h0, h1);
      w1.x = pk(h2, l0); w1.y = pk(l1, l2); w1.z = pk(s0, s1); w1.w = pk(s2, 0);
      rec[yl_] = w0;
      rec[2048 + yl_] = w1;
    }
    __syncthreads();

    // ---- 128 y-tiles: 1 ds_read_b128 + 2 MFMA + 4 v_min3 each ----
    #pragma unroll 4
    for (int tile = 0; tile < 128; ++tile) {
      short8 a = recp[aoff + tile * 16];
      f32x4 d0 = __builtin_amdgcn_mfma_f32_16x16x32_bf16(a, b0f, cz, 0, 0, 0);
      f32x4 d1 = __builtin_amdgcn_mfma_f32_16x16x32_bf16(a, b1f, cz, 0, 0, 0);
      float m0 = fminf(fminf(d0[0], d0[1]), d0[2]);
      gm0 = fminf(fminf(m0, d0[3]), gm0);
      float m1 = fminf(fminf(d1[0], d1[1]), d1[2]);
      gm1 = fminf(fminf(m1, d1[3]), gm1);
    }
    __syncthreads();
  }

  // ---- min across the 4 row-groups, add exact x^2, sum over the wave ----
  gm0 = fminf(gm0, __shfl_xor(gm0, 16, 64));
  gm0 = fminf(gm0, __shfl_xor(gm0, 32, 64));
  gm1 = fminf(gm1, __shfl_xor(gm1, 16, 64));
  gm1 = fminf(gm1, __shfl_xor(gm1, 32, 64));
  float v = (lane < 16) ? (gm0 + x2a) + (gm1 + x2b) : 0.0f;
  #pragma unroll
  for (int mm = 1; mm < 64; mm <<= 1) v += __shfl_xor(v, mm, 64);

  float* red = reinterpret_cast<float*>(rec);   // safe after last sync
  if (lane == 0) red[w] = v;
  __syncthreads();
  if (t == 0) sums[bid] = (red[0] + red[1]) + (red[2] + red[3]);
}

// Final combine: 512 block sums (L2-hot) into out[8]; single writer per
// batch, no atomics, no pre-zero. sums[bid], bid = (dir*8+b)*32 + xt.
__global__ __launch_bounds__(512) void chamfer_final_kernel(
    const float* __restrict__ sums, float* __restrict__ out)
{
  __shared__ float gred[16];
  int t = threadIdx.x;
  float v = sums[t];
  #pragma unroll
  for (int mm = 1; mm < 32; mm <<= 1) v += __shfl_xor(v, mm, 64);
  if ((t & 31) == 0) gred[t >> 5] = v;   // group = dir*8 + b
  __syncthreads();
  if (t < 8) out[t] = (gred[t] + gred[t + 8]) * (1.0f / 4096.0f);
}

// Fallback (workspace too small): exact-fp32 full-range direct kernel.
__global__ __launch_bounds__(BLK, 2) void chamfer_direct_kernel(
    const float* __restrict__ X, const float* __restrict__ Y,
    float* __restrict__ out)
{
  extern __shared__ float4 shd[];
  int lin = blockIdx.x;
  int xt  = lin & 1;  lin >>= 1;
  int b   = lin & 7;
  int dir = lin >> 3;
  const float* xs = (dir ? Y : X) + b * (NPTS * 3);
  const float* ys = (dir ? X : Y) + b * (NPTS * 3);

  for (int j = threadIdx.x; j < NPTS; j += BLK) {
    float y0 = ys[j * 3 + 0], y1 = ys[j * 3 + 1], y2 = ys[j * 3 + 2];
    shd[j] = make_float4(y0, y1, y2, 0.5f * (y0 * y0 + y1 * y1 + y2 * y2));
  }
  __syncthreads();

  int x0i = xt * (BLK * 8) + threadIdx.x * 8;
  float xf[24];
  const float4* xp = reinterpret_cast<const float4*>(xs + x0i * 3);
  #pragma unroll
  for (int i = 0; i < 6; ++i) {
    float4 p = xp[i];
    xf[i * 4 + 0] = p.x; xf[i * 4 + 1] = p.y;
    xf[i * 4 + 2] = p.z; xf[i * 4 + 3] = p.w;
  }
  float n0[8], n1[8], n2[8], x2h[8], gm[8];
  #pragma unroll
  for (int k = 0; k < 8; ++k) {
    float a = xf[k * 3 + 0], bb = xf[k * 3 + 1], cc = xf[k * 3 + 2];
    n0[k] = -a; n1[k] = -bb; n2[k] = -cc;
    x2h[k] = 0.5f * (a * a + bb * bb + cc * cc);
    gm[k] = __builtin_inff();
  }
  for (int j = 0; j < NPTS; j += 4) {
    float4 p0 = shd[j], p1 = shd[j + 1], p2 = shd[j + 2], p3 = shd[j + 3];
    #pragma unroll
    for (int k = 0; k < 8; ++k) {
      float ga = fmaf(n0[k], p0.x, fmaf(n1[k], p0.y, fmaf(n2[k], p0.z, p0.w)));
      float gb = fmaf(n0[k], p1.x, fmaf(n1[k], p1.y, fmaf(n2[k], p1.z, p1.w)));
      float gc = fmaf(n0[k], p2.x, fmaf(n1[k], p2.y, fmaf(n2[k], p2.z, p2.w)));
      float gd = fmaf(n0[k], p3.x, fmaf(n1[k], p3.y, fmaf(n2[k], p3.z, p3.w)));
      float m  = fminf(fminf(ga, gb), gc);
      gm[k] = fminf(fminf(m, gd), gm[k]);
    }
  }
  float v = 0.0f;
  #pragma unroll
  for (int k = 0; k < 8; ++k) v += 2.0f * (x2h[k] + gm[k]);
  #pragma unroll
  for (int off = 32; off > 0; off >>= 1) v += __shfl_down(v, off, 64);
  __syncthreads();
  float* red = reinterpret_cast<float*>(shd);
  if ((threadIdx.x & 63) == 0) red[threadIdx.x >> 6] = v;
  __syncthreads();
  if (threadIdx.x == 0) {
    float s2 = red[0] + red[1] + red[2] + red[3];
    atomicAdd(&out[b], s2 * (1.0f / 4096.0f));
  }
}

__global__ void zero_out_kernel(float* out)
{
  if (threadIdx.x < 8) out[threadIdx.x] = 0.0f;
}

extern "C" void kernel_launch(void* const* d_in, const int* in_sizes, int n_in,
                              void* d_out, int out_size, void* d_ws, size_t ws_size,
                              hipStream_t stream)
{
  const float* X = (const float*)d_in[0];
  const float* Y = (const float*)d_in[1];
  float* out = (float*)d_out;

  if (ws_size >= (size_t)(2 * 8 * XT) * sizeof(float)) {
    // 512 blocks = 2 dirs * 8 batches * 32 x-tiles; 2 blocks/CU (64 KiB LDS).
    chamfer_mfma_kernel<<<2 * 8 * XT, BLK, 0, stream>>>(X, Y, (float*)d_ws);
    chamfer_final_kernel<<<1, 512, 0, stream>>>((const float*)d_ws, out);
  } else {
    zero_out_kernel<<<1, 64, 0, stream>>>(out);
    chamfer_direct_kernel<<<2 * 8 * 2, BLK, NPTS * sizeof(float4), stream>>>(
        X, Y, out);
  }
}

// Round 3
// 67.118 us; speedup vs baseline: 1.2029x; 1.0560x over previous
//
#include <hip/hip_runtime.h>
#include <math.h>

#define BLK 256
#define NPTS 4096
#define XT 32             // x-tiles of 128 per (dir, b)

using short8 = __attribute__((ext_vector_type(8))) short;
using f32x16 = __attribute__((ext_vector_type(16))) float;

// bf16 RNE helpers (no NaN concern for this data).
__device__ inline unsigned short f2bf(float f) {
  unsigned u = __float_as_uint(f);
  return (unsigned short)((u + 0x7FFFu + ((u >> 16) & 1u)) >> 16);
}
__device__ inline float bf2f(unsigned short h) {
  return __uint_as_float((unsigned)h << 16);
}
__device__ inline unsigned pk(unsigned short lo, unsigned short hi) {
  return (unsigned)lo | ((unsigned)hi << 16);
}

// MFMA chamfer, 32x32x16 variant. Math: dist = (-2x.y + y^2)_MFMA + x^2_f32.
// K=16 slot map (A = y-record row, B = x col):
//   k0-2: yh_i * -2xh_i   k3-5: yl_i * -2xh_i
//   k6-8: yh_i * -2xl_i   k9-11: yl_i * -2xl_i
//   k12-14: y2h,y2m,y2l * 1.0   k15: 0
// 32x32x16 A-frag layout: lanes 0-31 hold k0-7 (record word0), lanes 32-63
// k8-15 (word1) -> each ds_read_b128 is fully distinct bytes (vs the 16x16
// version where half the wave was broadcast-duplicate).
//
// R2 post-mortem: kernel was DS-pipe-bound, not VALU - 4 waves/block each
// re-read ALL 4096 records (256 ds_read_b128/wave, ~24K cyc/CU for 8
// resident waves). Fix here: wave covers all 128 x (4 B-frags, 4 MFMA per
// A-read) x its own 1024-y slice -> 32 ds_read_b128/wave (8x less DS), MFMA
// 1024 cyc/wave (vs 2560). Binding pipe becomes the min-tree VALU floor:
// 1024 v_min3/wave (1 min per 4 pair-values, fundamental) + staging conv
// ~640 -> ~3.5us. Cross-wave min: 2KB LDS partials in epilogue.
//
// C/D (m74/m101): col=lane&31, row=(reg&3)+8*(reg>>2)+4*(lane>>5); rows
// covered by the two lane halves are complementary -> one shfl_xor(32) min.
// x^2 is col-constant => added exactly in fp32 AFTER the min.
//
// Harness context: ~40us of the window is the 256MiB ws re-poison
// (fillBufferAligned rows); ~21us is fixed dispatch overhead (constant
// across all rounds) - neither controllable from kernel code.
__global__ __launch_bounds__(BLK, 2) void chamfer_mfma_kernel(
    const float* __restrict__ X, const float* __restrict__ Y,
    float* __restrict__ sums)
{
  __shared__ uint4 rec[4096];   // [2][2048] SoA record words, 64 KiB

  int bid = blockIdx.x;
  int xt  = bid & 31;
  int b   = (bid >> 5) & 7;
  int dir = bid >> 8;

  const float* xs = (dir ? Y : X) + b * (NPTS * 3);
  const float* ys = (dir ? X : Y) + b * (NPTS * 3);

  int t = threadIdx.x;
  int lane = t & 63;
  int w = t >> 6;
  int half = lane >> 5;  // 0: k0-7 (word0), 1: k8-15 (word1)
  int c = lane & 31;     // x col within 32-col group

  // ---- B-frags: 4 x-groups of 32 cols, fixed for the whole kernel ----
  const unsigned short ONE = 0x3F80;
  short8 bf[4];
  #pragma unroll
  for (int xg = 0; xg < 4; ++xg) {
    const float* xp = xs + (xt * 128 + xg * 32 + c) * 3;
    float x0 = xp[0], x1 = xp[1], x2c = xp[2];
    unsigned short h0 = f2bf(x0), h1 = f2bf(x1), h2 = f2bf(x2c);
    unsigned short l0 = f2bf(x0 - bf2f(h0));
    unsigned short l1 = f2bf(x1 - bf2f(h1));
    unsigned short l2 = f2bf(x2c - bf2f(h2));
    unsigned short mh0 = f2bf(-2.0f * bf2f(h0));
    unsigned short mh1 = f2bf(-2.0f * bf2f(h1));
    unsigned short mh2 = f2bf(-2.0f * bf2f(h2));
    unsigned short ml0 = f2bf(-2.0f * bf2f(l0));
    unsigned short ml1 = f2bf(-2.0f * bf2f(l1));
    unsigned short ml2 = f2bf(-2.0f * bf2f(l2));
    short8 v;
    if (half == 0) {
      v[0] = mh0; v[1] = mh1; v[2] = mh2; v[3] = mh0;
      v[4] = mh1; v[5] = mh2; v[6] = ml0; v[7] = ml1;
    } else {
      v[0] = ml2; v[1] = ml0; v[2] = ml1; v[3] = ml2;
      v[4] = ONE; v[5] = ONE; v[6] = ONE; v[7] = 0;
    }
    bf[xg] = v;
  }

  float gm[4];
  #pragma unroll
  for (int xg = 0; xg < 4; ++xg) gm[xg] = __builtin_inff();
  f32x16 cz = {0.0f, 0.0f, 0.0f, 0.0f, 0.0f, 0.0f, 0.0f, 0.0f,
               0.0f, 0.0f, 0.0f, 0.0f, 0.0f, 0.0f, 0.0f, 0.0f};
  const short8* recp = reinterpret_cast<const short8*>(rec);
  int abase = half * 2048 + w * 512 + c;   // wave owns records [w*512, +512)

  for (int p = 0; p < 2; ++p) {
    // ---- stage 2048 y-records (SoA: word0 region, then word1 region) ----
    #pragma unroll
    for (int i = 0; i < 8; ++i) {
      int yl_ = t + i * 256;
      const float* yp = ys + (p * 2048 + yl_) * 3;
      float y0 = yp[0], y1 = yp[1], y2c = yp[2];
      unsigned short h0 = f2bf(y0), h1 = f2bf(y1), h2 = f2bf(y2c);
      unsigned short l0 = f2bf(y0 - bf2f(h0));
      unsigned short l1 = f2bf(y1 - bf2f(h1));
      unsigned short l2 = f2bf(y2c - bf2f(h2));
      float ysq = fmaf(y0, y0, fmaf(y1, y1, y2c * y2c));
      unsigned short s0 = f2bf(ysq);
      float r1 = ysq - bf2f(s0);
      unsigned short s1 = f2bf(r1);
      unsigned short s2 = f2bf(r1 - bf2f(s1));
      uint4 w0, w1;
      w0.x = pk(h0, h1); w0.y = pk(h2, l0); w0.z = pk(l1, l2); w0.w = pk(h0, h1);
      w1.x = pk(h2, l0); w1.y = pk(l1, l2); w1.z = pk(s0, s1); w1.w = pk(s2, 0);
      rec[yl_] = w0;
      rec[2048 + yl_] = w1;
    }
    __syncthreads();

    // ---- wave's 16 y-tiles of 32: 1 ds_read_b128 + 4 MFMA + 32 v_min3 ----
    #pragma unroll 4
    for (int tile = 0; tile < 16; ++tile) {
      short8 a = recp[abase + tile * 32];
      #pragma unroll
      for (int xg = 0; xg < 4; ++xg) {
        f32x16 d =
            __builtin_amdgcn_mfma_f32_32x32x16_bf16(a, bf[xg], cz, 0, 0, 0);
        float m0 = fminf(fminf(d[0], d[1]), d[2]);
        float m1 = fminf(fminf(d[3], d[4]), d[5]);
        float m2 = fminf(fminf(d[6], d[7]), d[8]);
        float m3 = fminf(fminf(d[9], d[10]), d[11]);
        float m4 = fminf(fminf(d[12], d[13]), d[14]);
        float n0 = fminf(fminf(m0, m1), m2);
        float n1 = fminf(fminf(m3, m4), d[15]);
        gm[xg] = fminf(fminf(n0, n1), gm[xg]);
      }
    }
    __syncthreads();
  }

  // ---- combine: lane halves, then cross-wave via 2KB LDS partials ----
  #pragma unroll
  for (int xg = 0; xg < 4; ++xg)
    gm[xg] = fminf(gm[xg], __shfl_xor(gm[xg], 32, 64));

  float* pf = reinterpret_cast<float*>(rec);   // safe after last sync
  if (lane < 32) {
    #pragma unroll
    for (int xg = 0; xg < 4; ++xg) pf[w * 128 + xg * 32 + c] = gm[xg];
  }
  __syncthreads();

  float v = 0.0f;
  if (t < 128) {   // waves 0,1: one x-point each
    float m = fminf(fminf(pf[t], pf[128 + t]), fminf(pf[256 + t], pf[384 + t]));
    const float* xp = xs + (xt * 128 + t) * 3;
    float a0 = xp[0], a1 = xp[1], a2 = xp[2];
    v = m + fmaf(a0, a0, fmaf(a1, a1, a2 * a2));
  }
  #pragma unroll
  for (int mm = 1; mm < 64; mm <<= 1) v += __shfl_xor(v, mm, 64);
  if (lane == 0 && t < 128) pf[512 + w] = v;   // distinct region, no hazard
  __syncthreads();
  if (t == 0) sums[bid] = pf[512] + pf[513];
}

// Final combine: 512 block sums (L2-hot) into out[8]; single writer per
// batch, no atomics, no pre-zero. sums[bid], bid = (dir*8+b)*32 + xt.
__global__ __launch_bounds__(512) void chamfer_final_kernel(
    const float* __restrict__ sums, float* __restrict__ out)
{
  __shared__ float gred[16];
  int t = threadIdx.x;
  float v = sums[t];
  #pragma unroll
  for (int mm = 1; mm < 32; mm <<= 1) v += __shfl_xor(v, mm, 64);
  if ((t & 31) == 0) gred[t >> 5] = v;   // group = dir*8 + b
  __syncthreads();
  if (t < 8) out[t] = (gred[t] + gred[t + 8]) * (1.0f / 4096.0f);
}

// Fallback (workspace too small): exact-fp32 full-range direct kernel.
__global__ __launch_bounds__(BLK, 2) void chamfer_direct_kernel(
    const float* __restrict__ X, const float* __restrict__ Y,
    float* __restrict__ out)
{
  extern __shared__ float4 shd[];
  int lin = blockIdx.x;
  int xt  = lin & 1;  lin >>= 1;
  int b   = lin & 7;
  int dir = lin >> 3;
  const float* xs = (dir ? Y : X) + b * (NPTS * 3);
  const float* ys = (dir ? X : Y) + b * (NPTS * 3);

  for (int j = threadIdx.x; j < NPTS; j += BLK) {
    float y0 = ys[j * 3 + 0], y1 = ys[j * 3 + 1], y2 = ys[j * 3 + 2];
    shd[j] = make_float4(y0, y1, y2, 0.5f * (y0 * y0 + y1 * y1 + y2 * y2));
  }
  __syncthreads();

  int x0i = xt * (BLK * 8) + threadIdx.x * 8;
  float xf[24];
  const float4* xp = reinterpret_cast<const float4*>(xs + x0i * 3);
  #pragma unroll
  for (int i = 0; i < 6; ++i) {
    float4 p = xp[i];
    xf[i * 4 + 0] = p.x; xf[i * 4 + 1] = p.y;
    xf[i * 4 + 2] = p.z; xf[i * 4 + 3] = p.w;
  }
  float n0[8], n1[8], n2[8], x2h[8], gm[8];
  #pragma unroll
  for (int k = 0; k < 8; ++k) {
    float a = xf[k * 3 + 0], bb = xf[k * 3 + 1], cc = xf[k * 3 + 2];
    n0[k] = -a; n1[k] = -bb; n2[k] = -cc;
    x2h[k] = 0.5f * (a * a + bb * bb + cc * cc);
    gm[k] = __builtin_inff();
  }
  for (int j = 0; j < NPTS; j += 4) {
    float4 p0 = shd[j], p1 = shd[j + 1], p2 = shd[j + 2], p3 = shd[j + 3];
    #pragma unroll
    for (int k = 0; k < 8; ++k) {
      float ga = fmaf(n0[k], p0.x, fmaf(n1[k], p0.y, fmaf(n2[k], p0.z, p0.w)));
      float gb = fmaf(n0[k], p1.x, fmaf(n1[k], p1.y, fmaf(n2[k], p1.z, p1.w)));
      float gc = fmaf(n0[k], p2.x, fmaf(n1[k], p2.y, fmaf(n2[k], p2.z, p2.w)));
      float gd = fmaf(n0[k], p3.x, fmaf(n1[k], p3.y, fmaf(n2[k], p3.z, p3.w)));
      float m  = fminf(fminf(ga, gb), gc);
      gm[k] = fminf(fminf(m, gd), gm[k]);
    }
  }
  float v = 0.0f;
  #pragma unroll
  for (int k = 0; k < 8; ++k) v += 2.0f * (x2h[k] + gm[k]);
  #pragma unroll
  for (int off = 32; off > 0; off >>= 1) v += __shfl_down(v, off, 64);
  __syncthreads();
  float* red = reinterpret_cast<float*>(shd);
  if ((threadIdx.x & 63) == 0) red[threadIdx.x >> 6] = v;
  __syncthreads();
  if (threadIdx.x == 0) {
    float s2 = red[0] + red[1] + red[2] + red[3];
    atomicAdd(&out[b], s2 * (1.0f / 4096.0f));
  }
}

__global__ void zero_out_kernel(float* out)
{
  if (threadIdx.x < 8) out[threadIdx.x] = 0.0f;
}

extern "C" void kernel_launch(void* const* d_in, const int* in_sizes, int n_in,
                              void* d_out, int out_size, void* d_ws, size_t ws_size,
                              hipStream_t stream)
{
  const float* X = (const float*)d_in[0];
  const float* Y = (const float*)d_in[1];
  float* out = (float*)d_out;

  if (ws_size >= (size_t)(2 * 8 * XT) * sizeof(float)) {
    // 512 blocks = 2 dirs * 8 batches * 32 x-tiles; 2 blocks/CU (64 KiB LDS).
    chamfer_mfma_kernel<<<2 * 8 * XT, BLK, 0, stream>>>(X, Y, (float*)d_ws);
    chamfer_final_kernel<<<1, 512, 0, stream>>>((const float*)d_ws, out);
  } else {
    zero_out_kernel<<<1, 64, 0, stream>>>(out);
    chamfer_direct_kernel<<<2 * 8 * 2, BLK, NPTS * sizeof(float4), stream>>>(
        X, Y, out);
  }
}